// Round 8
// baseline (288.107 us; speedup 1.0000x reference)
//
#include <hip/hip_runtime.h>
#include <hip/hip_bf16.h>
#include <stdint.h>

typedef __bf16 bf16x8 __attribute__((ext_vector_type(8)));
typedef __bf16 bf16x4 __attribute__((ext_vector_type(4)));
typedef float  f32x4  __attribute__((ext_vector_type(4)));

#define MFMA16(a, b, c) __builtin_amdgcn_mfma_f32_16x16x32_bf16((a), (b), (c), 0, 0, 0)

constexpr int BATCH = 4;
constexpr int TSEQ  = 2048;
constexpr int CDIM  = 1024;
constexpr int NHEAD = 16;
constexpr int HSZ   = 64;
constexpr size_t HEADELEMS = (size_t)BATCH * NHEAD * TSEQ * HSZ;  // 8388608

constexpr int LDF = 72;  // flash LDS stride (144 B)

// direct global->LDS DMA, 16 B per lane; LDS dest = wave-uniform base + lane*16
__device__ __forceinline__ void load_lds_128(const __bf16* g, __bf16* l) {
    __builtin_amdgcn_global_load_lds(
        (const __attribute__((address_space(1))) unsigned int*)g,
        (__attribute__((address_space(3))) unsigned int*)l,
        16, 0, 0);
}

// ---------------------------------------------------------------------------
// fp32 -> bf16 bulk convert (n multiple of 2048)
// ---------------------------------------------------------------------------
__global__ void conv_f32_bf16(const float* __restrict__ src, __bf16* __restrict__ dst, int n)
{
    const int i0 = (blockIdx.x * 256 + threadIdx.x) * 8;
    if (i0 >= n) return;
    float4 a = *(const float4*)(src + i0);
    float4 b = *(const float4*)(src + i0 + 4);
    bf16x8 o;
    o[0] = (__bf16)a.x; o[1] = (__bf16)a.y; o[2] = (__bf16)a.z; o[3] = (__bf16)a.w;
    o[4] = (__bf16)b.x; o[5] = (__bf16)b.y; o[6] = (__bf16)b.z; o[7] = (__bf16)b.w;
    *(bf16x8*)(dst + i0) = o;
}

// ---------------------------------------------------------------------------
// fp32 [K][N] -> bf16 transposed [N][K]. 32x32 LDS tiles, both sides coalesced.
// ---------------------------------------------------------------------------
__global__ void conv_transpose_bf16(const float* __restrict__ src, __bf16* __restrict__ dst,
                                    int K, int N)
{
    __shared__ __bf16 tile[32][33];
    const int n0 = blockIdx.x * 32, k0 = blockIdx.y * 32;
    const int tx = threadIdx.x & 31, ty = threadIdx.x >> 5;   // 32 x 8
    #pragma unroll
    for (int i = 0; i < 32; i += 8)
        tile[ty + i][tx] = (__bf16)src[(size_t)(k0 + ty + i) * N + n0 + tx];  // tile[k][n]
    __syncthreads();
    #pragma unroll
    for (int i = 0; i < 32; i += 8)
        dst[(size_t)(n0 + ty + i) * K + k0 + tx] = tile[tx][ty + i];          // dst[n][k]
}

// ---------------------------------------------------------------------------
// QKV GEMM, m97 structure + counted-vmcnt pipeline (VALIDATED r5/r6/r7:
// ~94 us, MfmaUtil 22.5, passed absmax 3x). 3 LDS buffers, depth-2 prefetch,
// vmcnt(4) per iter (never 0 mid-loop), raw s_barrier + sched_barrier(0).
// Epilogue: scatter q[b,h,t,d], k[b,h,t,d], v transposed [b,h,d,t] (bf16).
// ---------------------------------------------------------------------------
__global__ __launch_bounds__(256, 3)
void gemm_bt_pipe(const __bf16* __restrict__ A, const __bf16* __restrict__ BT,
                  const float* __restrict__ bias, __bf16* __restrict__ outp,
                  int M, int N, int K)
{
    __shared__ __bf16 As[3][128 * 32];   // [buf][row][k], unpadded
    __shared__ __bf16 Bs[3][128 * 32];

    const int t    = threadIdx.x;
    const int wave = t >> 6, lane = t & 63;
    const int quad = lane >> 4, l16 = lane & 15;
    const int bm = blockIdx.y * 128, bn = blockIdx.x * 128;
    const int wm = (wave >> 1) * 64, wn = (wave & 1) * 64;

    const int lrow = lane >> 2, lchunk = lane & 3;

    f32x4 acc[4][4];
    #pragma unroll
    for (int i = 0; i < 4; ++i)
        #pragma unroll
        for (int j = 0; j < 4; ++j)
            acc[i][j] = (f32x4){0.f, 0.f, 0.f, 0.f};

    const int c0 = wave * 2, c1 = wave * 2 + 1;
    const __bf16* a0 = A  + (size_t)(bm + 16 * c0 + lrow) * K + 8 * lchunk;
    const __bf16* a1 = A  + (size_t)(bm + 16 * c1 + lrow) * K + 8 * lchunk;
    const __bf16* b0 = BT + (size_t)(bn + 16 * c0 + lrow) * K + 8 * lchunk;
    const __bf16* b1 = BT + (size_t)(bn + 16 * c1 + lrow) * K + 8 * lchunk;

    const int nk = K >> 5;

#define STAGE(buf, kofs) do { \
    load_lds_128(a0 + (kofs), &As[buf][c0 * 512]); \
    load_lds_128(a1 + (kofs), &As[buf][c1 * 512]); \
    load_lds_128(b0 + (kofs), &Bs[buf][c0 * 512]); \
    load_lds_128(b1 + (kofs), &Bs[buf][c1 * 512]); } while (0)

    // prologue: tiles 0 and 1 in flight
    STAGE(0, 0);
    if (nk > 1) STAGE(1, 32);

    int cur = 0;
    for (int it = 0; it < nk; ++it) {
        if (it + 1 < nk) asm volatile("s_waitcnt vmcnt(4)" ::: "memory");
        else             asm volatile("s_waitcnt vmcnt(0)" ::: "memory");
        __builtin_amdgcn_s_barrier();
        __builtin_amdgcn_sched_barrier(0);

        if (it + 2 < nk) {
            const int stg = (cur >= 1) ? cur - 1 : cur + 2;   // (cur+2)%3
            STAGE(stg, (it + 2) * 32);
        }

        bf16x8 af[4], bfr[4];
        #pragma unroll
        for (int i = 0; i < 4; ++i)
            af[i]  = *(const bf16x8*)(&As[cur][(wm + i * 16 + l16) * 32 + quad * 8]);
        #pragma unroll
        for (int i = 0; i < 4; ++i)
            bfr[i] = *(const bf16x8*)(&Bs[cur][(wn + i * 16 + l16) * 32 + quad * 8]);
        #pragma unroll
        for (int mi = 0; mi < 4; ++mi)
            #pragma unroll
            for (int ni = 0; ni < 4; ++ni)
                acc[mi][ni] = MFMA16(af[mi], bfr[ni], acc[mi][ni]);

        cur = (cur + 1 >= 3) ? 0 : cur + 1;
    }
#undef STAGE

    #pragma unroll
    for (int ni = 0; ni < 4; ++ni) {
        const int col = bn + wn + ni * 16 + l16;          // 0..3071
        const float bv = bias[col];
        const int which = col >> 10;                      // 0=q 1=k 2=v
        const int c = col & 1023;
        const int h = c >> 6, d = c & 63;
        #pragma unroll
        for (int mi = 0; mi < 4; ++mi)
            #pragma unroll
            for (int r = 0; r < 4; ++r) {
                const int row = bm + wm + mi * 16 + quad * 4 + r;  // 0..8191
                const int bb = row >> 11, tt = row & 2047;
                size_t idx;
                if (which == 2)  // v transposed: [b,h,d,t]
                    idx = 2 * HEADELEMS + ((((size_t)bb * NHEAD + h) * HSZ + d) * TSEQ + tt);
                else
                    idx = (size_t)which * HEADELEMS
                        + ((((size_t)bb * NHEAD + h) * TSEQ + tt) * HSZ + d);
                outp[idx] = (__bf16)(acc[mi][ni][r] + bv);
            }
    }
}

// ---------------------------------------------------------------------------
// Projection GEMM: PROVEN m97 2-buffer structure (control). fp32 out + bias.
// ---------------------------------------------------------------------------
__global__ __launch_bounds__(256, 4)
void gemm_bt_proj(const __bf16* __restrict__ A, const __bf16* __restrict__ BT,
                  const float* __restrict__ bias, float* __restrict__ outp,
                  int M, int N, int K)
{
    __shared__ __bf16 As[2][128 * 32];   // [buf][row][k], unpadded
    __shared__ __bf16 Bs[2][128 * 32];

    const int t    = threadIdx.x;
    const int wave = t >> 6, lane = t & 63;
    const int quad = lane >> 4, l16 = lane & 15;
    const int bm = blockIdx.y * 128, bn = blockIdx.x * 128;
    const int wm = (wave >> 1) * 64, wn = (wave & 1) * 64;

    const int lrow = lane >> 2, lchunk = lane & 3;

    f32x4 acc[4][4];
    #pragma unroll
    for (int i = 0; i < 4; ++i)
        #pragma unroll
        for (int j = 0; j < 4; ++j)
            acc[i][j] = (f32x4){0.f, 0.f, 0.f, 0.f};

    const int c0 = wave * 2, c1 = wave * 2 + 1;
    const __bf16* a0 = A  + (size_t)(bm + 16 * c0 + lrow) * K + 8 * lchunk;
    const __bf16* a1 = A  + (size_t)(bm + 16 * c1 + lrow) * K + 8 * lchunk;
    const __bf16* b0 = BT + (size_t)(bn + 16 * c0 + lrow) * K + 8 * lchunk;
    const __bf16* b1 = BT + (size_t)(bn + 16 * c1 + lrow) * K + 8 * lchunk;

    const int nk = K >> 5;
    load_lds_128(a0, &As[0][c0 * 512]);
    load_lds_128(a1, &As[0][c1 * 512]);
    load_lds_128(b0, &Bs[0][c0 * 512]);
    load_lds_128(b1, &Bs[0][c1 * 512]);

    for (int it = 0; it < nk; ++it) {
        asm volatile("s_waitcnt vmcnt(0)" ::: "memory");
        __syncthreads();
        const int cur = it & 1, nxt = cur ^ 1;
        if (it + 1 < nk) {
            const int k0 = (it + 1) * 32;
            load_lds_128(a0 + k0, &As[nxt][c0 * 512]);
            load_lds_128(a1 + k0, &As[nxt][c1 * 512]);
            load_lds_128(b0 + k0, &Bs[nxt][c0 * 512]);
            load_lds_128(b1 + k0, &Bs[nxt][c1 * 512]);
        }

        bf16x8 af[4], bfr[4];
        #pragma unroll
        for (int i = 0; i < 4; ++i)
            af[i]  = *(const bf16x8*)(&As[cur][(wm + i * 16 + l16) * 32 + quad * 8]);
        #pragma unroll
        for (int i = 0; i < 4; ++i)
            bfr[i] = *(const bf16x8*)(&Bs[cur][(wn + i * 16 + l16) * 32 + quad * 8]);
        #pragma unroll
        for (int mi = 0; mi < 4; ++mi)
            #pragma unroll
            for (int ni = 0; ni < 4; ++ni)
                acc[mi][ni] = MFMA16(af[mi], bfr[ni], acc[mi][ni]);
    }

    #pragma unroll
    for (int ni = 0; ni < 4; ++ni) {
        const int col = bn + wn + ni * 16 + l16;
        const float bv = bias[col];
        #pragma unroll
        for (int mi = 0; mi < 4; ++mi)
            #pragma unroll
            for (int r = 0; r < 4; ++r) {
                const int row = bm + wm + mi * 16 + quad * 4 + r;
                outp[(size_t)row * N + col] = acc[mi][ni][r] + bv;
            }
    }
}

// ---------------------------------------------------------------------------
// Flash attention (causal), UNNORMALIZED, S^T formulation + ROUND-8 SPLIT-K.
// Q,K: [B*NH, T, 64]; V: [B*NH, 64, T] (transposed). Y: [B,T,C] bf16.
//
// Because this formulation tracks no running max (l = sum exp2(S), O = sum
// exp2(S)V), partials over disjoint key ranges are directly ADDABLE. So:
//   tiles 0..7  (2..16 key-iters): whole-tile blocks, write Y directly.
//   tiles 8..15 (18..34 key-iters): TWO half-key-range blocks each (9..16
//     iters), writing partial O (f32) + l to workspace; combine_norm sums
//     and normalizes. Staging is NOT duplicated (each half stages only its
//     own key range -- unlike the r6 mistake).
// Grid: 64 bh x 24 units = 1536 blocks at 4/CU (LDS unchanged): 1024
// co-resident + 512 refills; max block 16 iters vs slot-avg 17 -> near-LPT.
// Unit decode (work-descending for longest-first dispatch): j = u/3:
//   u%3<2 -> split tile qt=15-j, half=u%3;  u%3==2 -> whole tile qt=7-j.
// Inner loop is the proven round-0 code with [it0, it1) bounds.
// ---------------------------------------------------------------------------
__global__ __launch_bounds__(256, 4)
void flash_attn_sp(const __bf16* __restrict__ Q, const __bf16* __restrict__ Kg,
                   const __bf16* __restrict__ Vg, __bf16* __restrict__ Y,
                   float* __restrict__ Opart, float* __restrict__ lpart)
{
    __shared__ __bf16 Ks[64 * LDF];      // [key][d]
    __shared__ __bf16 Vs[64 * LDF];      // [d][key]
    __shared__ __bf16 Ps[4][32 * LDF];   // per-wave [q][key] (wave-private)

    const int t = threadIdx.x, wave = t >> 6, lane = t & 63;
    const int quad = lane >> 4, l16 = lane & 15;
    const int bh = blockIdx.x;
    const size_t base = (size_t)bh * TSEQ * HSZ;

    // ---- unit decode ----
    const int u = blockIdx.y, j = u / 3, m = u - 3 * j;
    const bool split = (m < 2);
    int qt, it0, it1;
    if (split) { qt = 15 - j; const int h0 = qt + 1; it0 = m ? h0 : 0; it1 = m ? 2 * qt + 2 : h0; }
    else       { qt = 7 - j;  it0 = 0; it1 = 2 * qt + 2; }
    const int q0 = qt * 128;

    const float sc = 0.125f * 1.44269504088896341f;  // log2(e)/sqrt(HS)

    // Q fragments (B-operand: n=l16 -> q row), pre-scaled by sc
    bf16x8 qf[2][2];
    #pragma unroll
    for (int mi = 0; mi < 2; ++mi) {
        const int qrow = q0 + wave * 32 + mi * 16 + l16;
        #pragma unroll
        for (int hh = 0; hh < 2; ++hh) {
            bf16x8 raw = *(const bf16x8*)(Q + base + (size_t)qrow * HSZ + hh * 32 + quad * 8);
            #pragma unroll
            for (int jj = 0; jj < 8; ++jj) qf[mi][hh][jj] = (__bf16)((float)raw[jj] * sc);
        }
    }

    bf16x8 ones;
    #pragma unroll
    for (int jj = 0; jj < 8; ++jj) ones[jj] = (__bf16)1.0f;

    f32x4 oacc[2][4];   // [mi][dt], C-layout row=q(quad*4+r), col=d(l16)
    f32x4 lacc[2];      // [mi],     row=q(quad*4+r), all cols equal
    #pragma unroll
    for (int mi = 0; mi < 2; ++mi) {
        lacc[mi] = (f32x4){0.f, 0.f, 0.f, 0.f};
        #pragma unroll
        for (int dt = 0; dt < 4; ++dt) oacc[mi][dt] = (f32x4){0.f, 0.f, 0.f, 0.f};
    }

    const int s_row = t >> 2, s_c16 = (t & 3) * 16;

    for (int it = it0; it < it1; ++it) {
        const int kt = it * 64;
        {   // stage K [key][d]
            const __bf16* kp = Kg + base + (size_t)(kt + s_row) * HSZ + s_c16;
            bf16x8 v0 = *(const bf16x8*)kp;
            bf16x8 v1 = *(const bf16x8*)(kp + 8);
            *(bf16x8*)(&Ks[s_row * LDF + s_c16])     = v0;
            *(bf16x8*)(&Ks[s_row * LDF + s_c16 + 8]) = v1;
        }
        {   // stage V [d][key]
            const __bf16* vp = Vg + base + (size_t)s_row * TSEQ + kt + s_c16;
            bf16x8 v0 = *(const bf16x8*)vp;
            bf16x8 v1 = *(const bf16x8*)(vp + 8);
            *(bf16x8*)(&Vs[s_row * LDF + s_c16])     = v0;
            *(bf16x8*)(&Vs[s_row * LDF + s_c16 + 8]) = v1;
        }
        __syncthreads();

        const bool active = (kt <= q0 + wave * 32 + 31);
        if (active) {
            // ---- S^T = K·Q^T : [4 key-tiles][2 q-tiles], row=key, col=q ----
            f32x4 st[4][2];
            #pragma unroll
            for (int ktl = 0; ktl < 4; ++ktl) {
                bf16x8 kf0 = *(const bf16x8*)(&Ks[(ktl * 16 + l16) * LDF + quad * 8]);
                bf16x8 kf1 = *(const bf16x8*)(&Ks[(ktl * 16 + l16) * LDF + 32 + quad * 8]);
                #pragma unroll
                for (int mi = 0; mi < 2; ++mi) {
                    f32x4 a = (f32x4){0.f, 0.f, 0.f, 0.f};
                    a = MFMA16(kf0, qf[mi][0], a);
                    a = MFMA16(kf1, qf[mi][1], a);
                    st[ktl][mi] = a;
                }
            }

            // ---- causal mask (near diagonal only) ----
            if (kt + 63 >= q0 + wave * 32) {
                #pragma unroll
                for (int ktl = 0; ktl < 4; ++ktl)
                    #pragma unroll
                    for (int mi = 0; mi < 2; ++mi)
                        #pragma unroll
                        for (int r = 0; r < 4; ++r) {
                            const int key = kt + ktl * 16 + quad * 4 + r;
                            const int qr  = q0 + wave * 32 + mi * 16 + l16;
                            if (key > qr) st[ktl][mi][r] = -1e30f;
                        }
            }

            // ---- P = exp2(S^T), packed b64 writes into Ps[q][key] ----
            #pragma unroll
            for (int ktl = 0; ktl < 4; ++ktl)
                #pragma unroll
                for (int mi = 0; mi < 2; ++mi) {
                    bf16x4 pv;
                    #pragma unroll
                    for (int r = 0; r < 4; ++r)
                        pv[r] = (__bf16)exp2f(st[ktl][mi][r]);
                    *(bf16x4*)(&Ps[wave][(mi * 16 + l16) * LDF + ktl * 16 + quad * 4]) = pv;
                }

            // wave-local fence: DS writes complete before reload
            asm volatile("s_waitcnt lgkmcnt(0)" ::: "memory");

            // ---- O += P·V^T, l += P·1 ----
            bf16x8 pf[2][2];
            #pragma unroll
            for (int mi = 0; mi < 2; ++mi) {
                pf[mi][0] = *(const bf16x8*)(&Ps[wave][(mi * 16 + l16) * LDF + quad * 8]);
                pf[mi][1] = *(const bf16x8*)(&Ps[wave][(mi * 16 + l16) * LDF + 32 + quad * 8]);
                lacc[mi] = MFMA16(pf[mi][0], ones, lacc[mi]);
                lacc[mi] = MFMA16(pf[mi][1], ones, lacc[mi]);
            }
            #pragma unroll
            for (int dt = 0; dt < 4; ++dt) {
                bf16x8 vf0 = *(const bf16x8*)(&Vs[(dt * 16 + l16) * LDF + quad * 8]);
                bf16x8 vf1 = *(const bf16x8*)(&Vs[(dt * 16 + l16) * LDF + 32 + quad * 8]);
                #pragma unroll
                for (int mi = 0; mi < 2; ++mi) {
                    oacc[mi][dt] = MFMA16(pf[mi][0], vf0, oacc[mi][dt]);
                    oacc[mi][dt] = MFMA16(pf[mi][1], vf1, oacc[mi][dt]);
                }
            }
        }
        __syncthreads();
    }

    if (!split) {
        // ---- whole tile: y = O / l, write Y directly ----
        const int b = bh >> 4, h = bh & 15;
        #pragma unroll
        for (int mi = 0; mi < 2; ++mi) {
            const f32x4 linv = {1.f / lacc[mi][0], 1.f / lacc[mi][1],
                                1.f / lacc[mi][2], 1.f / lacc[mi][3]};
            #pragma unroll
            for (int dt = 0; dt < 4; ++dt)
                #pragma unroll
                for (int r = 0; r < 4; ++r) {
                    const int tt = q0 + wave * 32 + mi * 16 + quad * 4 + r;
                    const int d  = dt * 16 + l16;
                    Y[((size_t)(b * TSEQ + tt) * CDIM) + h * HSZ + d] =
                        (__bf16)(oacc[mi][dt][r] * linv[r]);
                }
        }
    } else {
        // ---- split half: write f32 partials [half][bh][qt-8][row128][64] ----
        float* Op = Opart + ((((size_t)m * 64 + bh) * 8 + (qt - 8)) * 128) * 64;
        float* lp = lpart + (((size_t)m * 64 + bh) * 8 + (qt - 8)) * 128;
        #pragma unroll
        for (int mi = 0; mi < 2; ++mi) {
            #pragma unroll
            for (int dt = 0; dt < 4; ++dt)
                #pragma unroll
                for (int r = 0; r < 4; ++r) {
                    const int row = wave * 32 + mi * 16 + quad * 4 + r;  // 0..127
                    Op[(size_t)row * 64 + dt * 16 + l16] = oacc[mi][dt][r];
                }
            if (l16 == 0) {
                #pragma unroll
                for (int r = 0; r < 4; ++r)
                    lp[wave * 32 + mi * 16 + quad * 4 + r] = lacc[mi][r];
            }
        }
    }
}

// ---------------------------------------------------------------------------
// Combine split-K partials: y = (O0+O1)/(l0+l1) for tiles 8..15.
// Grid: 64 bh x 8 tiles, 256 threads; each thread: one row-half (32 cols).
// ---------------------------------------------------------------------------
__global__ __launch_bounds__(256)
void combine_norm(const float* __restrict__ Opart, const float* __restrict__ lpart,
                  __bf16* __restrict__ Y)
{
    const int bh = blockIdx.x, qt8 = blockIdx.y, t = threadIdx.x;
    const int qt = 8 + qt8, q0 = qt * 128;
    const int row = t >> 1, ch = (t & 1) * 32;

    const size_t o0 = ((((size_t)0 * 64 + bh) * 8 + qt8) * 128 + row) * 64 + ch;
    const size_t o1 = ((((size_t)1 * 64 + bh) * 8 + qt8) * 128 + row) * 64 + ch;
    const float l0 = lpart[(((size_t)0 * 64 + bh) * 8 + qt8) * 128 + row];
    const float l1 = lpart[(((size_t)1 * 64 + bh) * 8 + qt8) * 128 + row];
    const float inv = 1.f / (l0 + l1);

    const int b = bh >> 4, h = bh & 15;
    __bf16* yp = Y + ((size_t)(b * TSEQ + q0 + row) * CDIM) + h * HSZ + ch;

    #pragma unroll
    for (int j = 0; j < 4; ++j) {
        float4 a0 = *(const float4*)(Opart + o0 + j * 8);
        float4 a1 = *(const float4*)(Opart + o0 + j * 8 + 4);
        float4 b0 = *(const float4*)(Opart + o1 + j * 8);
        float4 b1 = *(const float4*)(Opart + o1 + j * 8 + 4);
        bf16x8 o;
        o[0] = (__bf16)((a0.x + b0.x) * inv);
        o[1] = (__bf16)((a0.y + b0.y) * inv);
        o[2] = (__bf16)((a0.z + b0.z) * inv);
        o[3] = (__bf16)((a0.w + b0.w) * inv);
        o[4] = (__bf16)((a1.x + b1.x) * inv);
        o[5] = (__bf16)((a1.y + b1.y) * inv);
        o[6] = (__bf16)((a1.z + b1.z) * inv);
        o[7] = (__bf16)((a1.w + b1.w) * inv);
        *(bf16x8*)(yp + j * 8) = o;
    }
}

// ---------------------------------------------------------------------------
extern "C" void kernel_launch(void* const* d_in, const int* in_sizes, int n_in,
                              void* d_out, int out_size, void* d_ws, size_t ws_size,
                              hipStream_t stream)
{
    const int NX = 8388608, NWA = 3145728, NWP = 1048576;
    char* wsb = (char*)d_ws;

    size_t off = 0;
    __bf16* cx   = (__bf16*)(wsb + off); off += (size_t)2 * NX;
    __bf16* cwaT = (__bf16*)(wsb + off); off += (size_t)2 * NWA;   // [3072][1024]
    __bf16* cwpT = (__bf16*)(wsb + off); off += (size_t)2 * NWP;   // [1024][1024]
    __bf16* q    = (__bf16*)(wsb + off);
    __bf16* y    = q + 3 * HEADELEMS;
    float*  Opart = (float*)(y + HEADELEMS);                        // 33.5 MB
    float*  lpart = Opart + (size_t)2 * 64 * 8 * 128 * 64;          // 0.5 MB

    const float* xf = (const float*)d_in[0];
    const float* ba = (const float*)d_in[2];
    const float* bp = (const float*)d_in[4];

    conv_f32_bf16<<<NX / 2048, 256, 0, stream>>>(xf, cx, NX);
    conv_transpose_bf16<<<dim3(3 * CDIM / 32, CDIM / 32), 256, 0, stream>>>(
        (const float*)d_in[1], cwaT, CDIM, 3 * CDIM);
    conv_transpose_bf16<<<dim3(CDIM / 32, CDIM / 32), 256, 0, stream>>>(
        (const float*)d_in[3], cwpT, CDIM, CDIM);

    // qkv = x @ W_attn + b_attn -> q/k [b,h,t,d], v [b,h,d,t]  (validated pipe)
    gemm_bt_pipe<<<dim3(3 * CDIM / 128, BATCH * TSEQ / 128), 256, 0, stream>>>(
        cx, cwaT, ba, q, BATCH * TSEQ, 3 * CDIM, CDIM);

    // causal flash attention, split-K for long tiles -> y + partials
    flash_attn_sp<<<dim3(BATCH * NHEAD, 24), 256, 0, stream>>>(
        q, q + HEADELEMS, q + 2 * HEADELEMS, y, Opart, lpart);

    // combine partials for tiles 8..15
    combine_norm<<<dim3(BATCH * NHEAD, 8), 256, 0, stream>>>(Opart, lpart, y);

    // out = y @ W_proj + b_proj (fp32 out) -- proven 2-buffer control
    gemm_bt_proj<<<dim3(CDIM / 128, BATCH * TSEQ / 128), 256, 0, stream>>>(
        y, cwpT, bp, (float*)d_out, BATCH * TSEQ, CDIM, CDIM);
}

// Round 9
// 266.761 us; speedup vs baseline: 1.0800x; 1.0800x over previous
//
#include <hip/hip_runtime.h>
#include <hip/hip_bf16.h>
#include <stdint.h>

typedef __bf16 bf16x8 __attribute__((ext_vector_type(8)));
typedef __bf16 bf16x4 __attribute__((ext_vector_type(4)));
typedef float  f32x4  __attribute__((ext_vector_type(4)));

#define MFMA16(a, b, c) __builtin_amdgcn_mfma_f32_16x16x32_bf16((a), (b), (c), 0, 0, 0)

constexpr int BATCH = 4;
constexpr int TSEQ  = 2048;
constexpr int CDIM  = 1024;
constexpr int NHEAD = 16;
constexpr int HSZ   = 64;
constexpr size_t HEADELEMS = (size_t)BATCH * NHEAD * TSEQ * HSZ;  // 8388608

constexpr int LDF = 72;  // flash LDS stride (144 B)

// direct global->LDS DMA, 16 B per lane; LDS dest = wave-uniform base + lane*16
__device__ __forceinline__ void load_lds_128(const __bf16* g, __bf16* l) {
    __builtin_amdgcn_global_load_lds(
        (const __attribute__((address_space(1))) unsigned int*)g,
        (__attribute__((address_space(3))) unsigned int*)l,
        16, 0, 0);
}

// ---------------------------------------------------------------------------
// fp32 -> bf16 bulk convert (n multiple of 2048)
// ---------------------------------------------------------------------------
__global__ void conv_f32_bf16(const float* __restrict__ src, __bf16* __restrict__ dst, int n)
{
    const int i0 = (blockIdx.x * 256 + threadIdx.x) * 8;
    if (i0 >= n) return;
    float4 a = *(const float4*)(src + i0);
    float4 b = *(const float4*)(src + i0 + 4);
    bf16x8 o;
    o[0] = (__bf16)a.x; o[1] = (__bf16)a.y; o[2] = (__bf16)a.z; o[3] = (__bf16)a.w;
    o[4] = (__bf16)b.x; o[5] = (__bf16)b.y; o[6] = (__bf16)b.z; o[7] = (__bf16)b.w;
    *(bf16x8*)(dst + i0) = o;
}

// ---------------------------------------------------------------------------
// fp32 [K][N] -> bf16 transposed [N][K]. 32x32 LDS tiles, both sides coalesced.
// ---------------------------------------------------------------------------
__global__ void conv_transpose_bf16(const float* __restrict__ src, __bf16* __restrict__ dst,
                                    int K, int N)
{
    __shared__ __bf16 tile[32][33];
    const int n0 = blockIdx.x * 32, k0 = blockIdx.y * 32;
    const int tx = threadIdx.x & 31, ty = threadIdx.x >> 5;   // 32 x 8
    #pragma unroll
    for (int i = 0; i < 32; i += 8)
        tile[ty + i][tx] = (__bf16)src[(size_t)(k0 + ty + i) * N + n0 + tx];  // tile[k][n]
    __syncthreads();
    #pragma unroll
    for (int i = 0; i < 32; i += 8)
        dst[(size_t)(n0 + ty + i) * K + k0 + tx] = tile[tx][ty + i];          // dst[n][k]
}

// ---------------------------------------------------------------------------
// QKV GEMM, m97 structure + counted-vmcnt pipeline (VALIDATED r5/r6/r7/r8:
// ~94.5 us, MfmaUtil 22.5, passed absmax 4x). 3 LDS buffers, depth-2
// prefetch, vmcnt(4) per iter (never 0 mid-loop), raw s_barrier +
// sched_barrier(0).
// ROUND-9: + T1 XCD-aware bijective blockIdx swizzle. Measured FETCH_SIZE
// 71.75 MB vs 22.5 MB compulsory = 3.2x over-fetch; consecutive blocks
// share an A-panel but round-robin across 8 XCD-private L2s. Swizzle gives
// each XCD a contiguous chunk (nwg=1536, %8==0 -> simple form bijective).
// Epilogue: scatter q[b,h,t,d], k[b,h,t,d], v transposed [b,h,d,t] (bf16).
// ---------------------------------------------------------------------------
__global__ __launch_bounds__(256, 3)
void gemm_bt_pipe(const __bf16* __restrict__ A, const __bf16* __restrict__ BT,
                  const float* __restrict__ bias, __bf16* __restrict__ outp,
                  int M, int N, int K)
{
    __shared__ __bf16 As[3][128 * 32];   // [buf][row][k], unpadded
    __shared__ __bf16 Bs[3][128 * 32];

    const int t    = threadIdx.x;
    const int wave = t >> 6, lane = t & 63;
    const int quad = lane >> 4, l16 = lane & 15;

    // T1 XCD swizzle: hw-dispatch id -> logical tile id, contiguous per XCD
    const int nbx = (int)gridDim.x;
    int lin = (int)blockIdx.y * nbx + (int)blockIdx.x;
    {
        const int cpx = (nbx * (int)gridDim.y) >> 3;   // nwg % 8 == 0
        lin = (lin & 7) * cpx + (lin >> 3);
    }
    const int bm = (lin / nbx) * 128, bn = (lin % nbx) * 128;
    const int wm = (wave >> 1) * 64, wn = (wave & 1) * 64;

    const int lrow = lane >> 2, lchunk = lane & 3;

    f32x4 acc[4][4];
    #pragma unroll
    for (int i = 0; i < 4; ++i)
        #pragma unroll
        for (int j = 0; j < 4; ++j)
            acc[i][j] = (f32x4){0.f, 0.f, 0.f, 0.f};

    const int c0 = wave * 2, c1 = wave * 2 + 1;
    const __bf16* a0 = A  + (size_t)(bm + 16 * c0 + lrow) * K + 8 * lchunk;
    const __bf16* a1 = A  + (size_t)(bm + 16 * c1 + lrow) * K + 8 * lchunk;
    const __bf16* b0 = BT + (size_t)(bn + 16 * c0 + lrow) * K + 8 * lchunk;
    const __bf16* b1 = BT + (size_t)(bn + 16 * c1 + lrow) * K + 8 * lchunk;

    const int nk = K >> 5;

#define STAGE(buf, kofs) do { \
    load_lds_128(a0 + (kofs), &As[buf][c0 * 512]); \
    load_lds_128(a1 + (kofs), &As[buf][c1 * 512]); \
    load_lds_128(b0 + (kofs), &Bs[buf][c0 * 512]); \
    load_lds_128(b1 + (kofs), &Bs[buf][c1 * 512]); } while (0)

    // prologue: tiles 0 and 1 in flight
    STAGE(0, 0);
    if (nk > 1) STAGE(1, 32);

    int cur = 0;
    for (int it = 0; it < nk; ++it) {
        if (it + 1 < nk) asm volatile("s_waitcnt vmcnt(4)" ::: "memory");
        else             asm volatile("s_waitcnt vmcnt(0)" ::: "memory");
        __builtin_amdgcn_s_barrier();
        __builtin_amdgcn_sched_barrier(0);

        if (it + 2 < nk) {
            const int stg = (cur >= 1) ? cur - 1 : cur + 2;   // (cur+2)%3
            STAGE(stg, (it + 2) * 32);
        }

        bf16x8 af[4], bfr[4];
        #pragma unroll
        for (int i = 0; i < 4; ++i)
            af[i]  = *(const bf16x8*)(&As[cur][(wm + i * 16 + l16) * 32 + quad * 8]);
        #pragma unroll
        for (int i = 0; i < 4; ++i)
            bfr[i] = *(const bf16x8*)(&Bs[cur][(wn + i * 16 + l16) * 32 + quad * 8]);
        #pragma unroll
        for (int mi = 0; mi < 4; ++mi)
            #pragma unroll
            for (int ni = 0; ni < 4; ++ni)
                acc[mi][ni] = MFMA16(af[mi], bfr[ni], acc[mi][ni]);

        cur = (cur + 1 >= 3) ? 0 : cur + 1;
    }
#undef STAGE

    #pragma unroll
    for (int ni = 0; ni < 4; ++ni) {
        const int col = bn + wn + ni * 16 + l16;          // 0..3071
        const float bv = bias[col];
        const int which = col >> 10;                      // 0=q 1=k 2=v
        const int c = col & 1023;
        const int h = c >> 6, d = c & 63;
        #pragma unroll
        for (int mi = 0; mi < 4; ++mi)
            #pragma unroll
            for (int r = 0; r < 4; ++r) {
                const int row = bm + wm + mi * 16 + quad * 4 + r;  // 0..8191
                const int bb = row >> 11, tt = row & 2047;
                size_t idx;
                if (which == 2)  // v transposed: [b,h,d,t]
                    idx = 2 * HEADELEMS + ((((size_t)bb * NHEAD + h) * HSZ + d) * TSEQ + tt);
                else
                    idx = (size_t)which * HEADELEMS
                        + ((((size_t)bb * NHEAD + h) * TSEQ + tt) * HSZ + d);
                outp[idx] = (__bf16)(acc[mi][ni][r] + bv);
            }
    }
}

// ---------------------------------------------------------------------------
// Projection GEMM: PROVEN m97 2-buffer structure + T1 XCD swizzle (r9).
// nwg = 8 x 64 = 512, %8 == 0 -> bijective. fp32 out + bias.
// ---------------------------------------------------------------------------
__global__ __launch_bounds__(256, 4)
void gemm_bt_proj(const __bf16* __restrict__ A, const __bf16* __restrict__ BT,
                  const float* __restrict__ bias, float* __restrict__ outp,
                  int M, int N, int K)
{
    __shared__ __bf16 As[2][128 * 32];   // [buf][row][k], unpadded
    __shared__ __bf16 Bs[2][128 * 32];

    const int t    = threadIdx.x;
    const int wave = t >> 6, lane = t & 63;
    const int quad = lane >> 4, l16 = lane & 15;

    const int nbx = (int)gridDim.x;
    int lin = (int)blockIdx.y * nbx + (int)blockIdx.x;
    {
        const int cpx = (nbx * (int)gridDim.y) >> 3;   // nwg % 8 == 0
        lin = (lin & 7) * cpx + (lin >> 3);
    }
    const int bm = (lin / nbx) * 128, bn = (lin % nbx) * 128;
    const int wm = (wave >> 1) * 64, wn = (wave & 1) * 64;

    const int lrow = lane >> 2, lchunk = lane & 3;

    f32x4 acc[4][4];
    #pragma unroll
    for (int i = 0; i < 4; ++i)
        #pragma unroll
        for (int j = 0; j < 4; ++j)
            acc[i][j] = (f32x4){0.f, 0.f, 0.f, 0.f};

    const int c0 = wave * 2, c1 = wave * 2 + 1;
    const __bf16* a0 = A  + (size_t)(bm + 16 * c0 + lrow) * K + 8 * lchunk;
    const __bf16* a1 = A  + (size_t)(bm + 16 * c1 + lrow) * K + 8 * lchunk;
    const __bf16* b0 = BT + (size_t)(bn + 16 * c0 + lrow) * K + 8 * lchunk;
    const __bf16* b1 = BT + (size_t)(bn + 16 * c1 + lrow) * K + 8 * lchunk;

    const int nk = K >> 5;
    load_lds_128(a0, &As[0][c0 * 512]);
    load_lds_128(a1, &As[0][c1 * 512]);
    load_lds_128(b0, &Bs[0][c0 * 512]);
    load_lds_128(b1, &Bs[0][c1 * 512]);

    for (int it = 0; it < nk; ++it) {
        // REQUIRED: drain this wave's global_load_lds DMA before the barrier so
        // the staged tile is visible to other waves' ds_reads after it.
        asm volatile("s_waitcnt vmcnt(0)" ::: "memory");
        __syncthreads();
        const int cur = it & 1, nxt = cur ^ 1;
        if (it + 1 < nk) {
            const int k0 = (it + 1) * 32;
            load_lds_128(a0 + k0, &As[nxt][c0 * 512]);
            load_lds_128(a1 + k0, &As[nxt][c1 * 512]);
            load_lds_128(b0 + k0, &Bs[nxt][c0 * 512]);
            load_lds_128(b1 + k0, &Bs[nxt][c1 * 512]);
        }

        bf16x8 af[4], bfr[4];
        #pragma unroll
        for (int i = 0; i < 4; ++i)
            af[i]  = *(const bf16x8*)(&As[cur][(wm + i * 16 + l16) * 32 + quad * 8]);
        #pragma unroll
        for (int i = 0; i < 4; ++i)
            bfr[i] = *(const bf16x8*)(&Bs[cur][(wn + i * 16 + l16) * 32 + quad * 8]);
        #pragma unroll
        for (int mi = 0; mi < 4; ++mi)
            #pragma unroll
            for (int ni = 0; ni < 4; ++ni)
                acc[mi][ni] = MFMA16(af[mi], bfr[ni], acc[mi][ni]);
    }

    #pragma unroll
    for (int ni = 0; ni < 4; ++ni) {
        const int col = bn + wn + ni * 16 + l16;
        const float bv = bias[col];
        #pragma unroll
        for (int mi = 0; mi < 4; ++mi)
            #pragma unroll
            for (int r = 0; r < 4; ++r) {
                const int row = bm + wm + mi * 16 + quad * 4 + r;
                outp[(size_t)row * N + col] = acc[mi][ni][r] + bv;
            }
    }
}

// ---------------------------------------------------------------------------
// Flash attention (causal), UNNORMALIZED, S^T formulation -- the r0/r5
// PROVEN structure (92.5 us, Occ 28%). FROZEN: four restructures (T14
// reg-prefetch, 2-wave blocks, causal pairing, split-K) all regressed
// +5..+19 us; this is a robust local optimum. Remaining headroom needs the
// co-designed 8-warp ladder, not piecewise grafts.
// Q,K: [B*NH, T, 64]; V: [B*NH, 64, T] (transposed). Y: [B,T,C] bf16.
// ---------------------------------------------------------------------------
__global__ __launch_bounds__(256, 4)
void flash_attn(const __bf16* __restrict__ Q, const __bf16* __restrict__ Kg,
                const __bf16* __restrict__ Vg, __bf16* __restrict__ Y)
{
    __shared__ __bf16 Ks[64 * LDF];      // [key][d]
    __shared__ __bf16 Vs[64 * LDF];      // [d][key]
    __shared__ __bf16 Ps[4][32 * LDF];   // per-wave [q][key] (wave-private)

    const int t = threadIdx.x, wave = t >> 6, lane = t & 63;
    const int quad = lane >> 4, l16 = lane & 15;
    const int bh = blockIdx.x;
    const int q0 = ((int)gridDim.y - 1 - (int)blockIdx.y) * 128;  // longest first
    const size_t base = (size_t)bh * TSEQ * HSZ;

    const float sc = 0.125f * 1.44269504088896341f;  // log2(e)/sqrt(HS)

    // Q fragments (B-operand: n=l16 -> q row), pre-scaled by sc
    bf16x8 qf[2][2];
    #pragma unroll
    for (int mi = 0; mi < 2; ++mi) {
        const int qrow = q0 + wave * 32 + mi * 16 + l16;
        #pragma unroll
        for (int h = 0; h < 2; ++h) {
            bf16x8 raw = *(const bf16x8*)(Q + base + (size_t)qrow * HSZ + h * 32 + quad * 8);
            #pragma unroll
            for (int j = 0; j < 8; ++j) qf[mi][h][j] = (__bf16)((float)raw[j] * sc);
        }
    }

    bf16x8 ones;
    #pragma unroll
    for (int j = 0; j < 8; ++j) ones[j] = (__bf16)1.0f;

    f32x4 oacc[2][4];   // [mi][dt], C-layout row=q(quad*4+r), col=d(l16)
    f32x4 lacc[2];      // [mi],     row=q(quad*4+r), all cols equal
    #pragma unroll
    for (int mi = 0; mi < 2; ++mi) {
        lacc[mi] = (f32x4){0.f, 0.f, 0.f, 0.f};
        #pragma unroll
        for (int dt = 0; dt < 4; ++dt) oacc[mi][dt] = (f32x4){0.f, 0.f, 0.f, 0.f};
    }

    const int s_row = t >> 2, s_c16 = (t & 3) * 16;

    const int iters = q0 / 64 + 2;
    for (int it = 0; it < iters; ++it) {
        const int kt = it * 64;
        {   // stage K [key][d]
            const __bf16* kp = Kg + base + (size_t)(kt + s_row) * HSZ + s_c16;
            bf16x8 v0 = *(const bf16x8*)kp;
            bf16x8 v1 = *(const bf16x8*)(kp + 8);
            *(bf16x8*)(&Ks[s_row * LDF + s_c16])     = v0;
            *(bf16x8*)(&Ks[s_row * LDF + s_c16 + 8]) = v1;
        }
        {   // stage V [d][key]
            const __bf16* vp = Vg + base + (size_t)s_row * TSEQ + kt + s_c16;
            bf16x8 v0 = *(const bf16x8*)vp;
            bf16x8 v1 = *(const bf16x8*)(vp + 8);
            *(bf16x8*)(&Vs[s_row * LDF + s_c16])     = v0;
            *(bf16x8*)(&Vs[s_row * LDF + s_c16 + 8]) = v1;
        }
        __syncthreads();

        const bool active = (kt <= q0 + wave * 32 + 31);
        if (active) {
            // ---- S^T = K·Q^T : [4 key-tiles][2 q-tiles], C row=key, col=q ----
            f32x4 st[4][2];
            #pragma unroll
            for (int ktl = 0; ktl < 4; ++ktl) {
                bf16x8 kf0 = *(const bf16x8*)(&Ks[(ktl * 16 + l16) * LDF + quad * 8]);
                bf16x8 kf1 = *(const bf16x8*)(&Ks[(ktl * 16 + l16) * LDF + 32 + quad * 8]);
                #pragma unroll
                for (int mi = 0; mi < 2; ++mi) {
                    f32x4 a = (f32x4){0.f, 0.f, 0.f, 0.f};
                    a = MFMA16(kf0, qf[mi][0], a);
                    a = MFMA16(kf1, qf[mi][1], a);
                    st[ktl][mi] = a;
                }
            }

            // ---- causal mask (near diagonal only) ----
            if (kt + 63 >= q0 + wave * 32) {
                #pragma unroll
                for (int ktl = 0; ktl < 4; ++ktl)
                    #pragma unroll
                    for (int mi = 0; mi < 2; ++mi)
                        #pragma unroll
                        for (int r = 0; r < 4; ++r) {
                            const int key = kt + ktl * 16 + quad * 4 + r;
                            const int qr  = q0 + wave * 32 + mi * 16 + l16;
                            if (key > qr) st[ktl][mi][r] = -1e30f;
                        }
            }

            // ---- P = exp2(S^T), packed b64 writes into Ps[q][key] ----
            #pragma unroll
            for (int ktl = 0; ktl < 4; ++ktl)
                #pragma unroll
                for (int mi = 0; mi < 2; ++mi) {
                    bf16x4 pv;
                    #pragma unroll
                    for (int r = 0; r < 4; ++r)
                        pv[r] = (__bf16)exp2f(st[ktl][mi][r]);
                    *(bf16x4*)(&Ps[wave][(mi * 16 + l16) * LDF + ktl * 16 + quad * 4]) = pv;
                }

            // wave-local fence: DS writes complete before reload (wave-private Ps)
            asm volatile("s_waitcnt lgkmcnt(0)" ::: "memory");

            // ---- O += P·V^T, l += P·1 ----
            bf16x8 pf[2][2];
            #pragma unroll
            for (int mi = 0; mi < 2; ++mi) {
                pf[mi][0] = *(const bf16x8*)(&Ps[wave][(mi * 16 + l16) * LDF + quad * 8]);
                pf[mi][1] = *(const bf16x8*)(&Ps[wave][(mi * 16 + l16) * LDF + 32 + quad * 8]);
                lacc[mi] = MFMA16(pf[mi][0], ones, lacc[mi]);
                lacc[mi] = MFMA16(pf[mi][1], ones, lacc[mi]);
            }
            #pragma unroll
            for (int dt = 0; dt < 4; ++dt) {
                bf16x8 vf0 = *(const bf16x8*)(&Vs[(dt * 16 + l16) * LDF + quad * 8]);
                bf16x8 vf1 = *(const bf16x8*)(&Vs[(dt * 16 + l16) * LDF + 32 + quad * 8]);
                #pragma unroll
                for (int mi = 0; mi < 2; ++mi) {
                    oacc[mi][dt] = MFMA16(pf[mi][0], vf0, oacc[mi][dt]);
                    oacc[mi][dt] = MFMA16(pf[mi][1], vf1, oacc[mi][dt]);
                }
            }
        }
        __syncthreads();
    }

    // ---- epilogue: y = O / l (both C-layout, no cross-lane moves) ----
    const int b = bh >> 4, h = bh & 15;
    #pragma unroll
    for (int mi = 0; mi < 2; ++mi) {
        const f32x4 linv = {1.f / lacc[mi][0], 1.f / lacc[mi][1],
                            1.f / lacc[mi][2], 1.f / lacc[mi][3]};
        #pragma unroll
        for (int dt = 0; dt < 4; ++dt)
            #pragma unroll
            for (int r = 0; r < 4; ++r) {
                const int tt = q0 + wave * 32 + mi * 16 + quad * 4 + r;
                const int d  = dt * 16 + l16;
                Y[((size_t)(b * TSEQ + tt) * CDIM) + h * HSZ + d] =
                    (__bf16)(oacc[mi][dt][r] * linv[r]);
            }
    }
}

// ---------------------------------------------------------------------------
extern "C" void kernel_launch(void* const* d_in, const int* in_sizes, int n_in,
                              void* d_out, int out_size, void* d_ws, size_t ws_size,
                              hipStream_t stream)
{
    const int NX = 8388608, NWA = 3145728, NWP = 1048576;
    char* wsb = (char*)d_ws;

    size_t off = 0;
    __bf16* cx   = (__bf16*)(wsb + off); off += (size_t)2 * NX;
    __bf16* cwaT = (__bf16*)(wsb + off); off += (size_t)2 * NWA;   // [3072][1024]
    __bf16* cwpT = (__bf16*)(wsb + off); off += (size_t)2 * NWP;   // [1024][1024]
    __bf16* q    = (__bf16*)(wsb + off);
    __bf16* y    = q + 3 * HEADELEMS;

    const float* xf = (const float*)d_in[0];
    const float* ba = (const float*)d_in[2];
    const float* bp = (const float*)d_in[4];

    conv_f32_bf16<<<NX / 2048, 256, 0, stream>>>(xf, cx, NX);
    conv_transpose_bf16<<<dim3(3 * CDIM / 32, CDIM / 32), 256, 0, stream>>>(
        (const float*)d_in[1], cwaT, CDIM, 3 * CDIM);
    conv_transpose_bf16<<<dim3(CDIM / 32, CDIM / 32), 256, 0, stream>>>(
        (const float*)d_in[3], cwpT, CDIM, CDIM);

    // qkv = x @ W_attn + b_attn -> q/k [b,h,t,d], v [b,h,d,t]
    // (validated counted-vmcnt pipe + T1 XCD swizzle)
    gemm_bt_pipe<<<dim3(3 * CDIM / 128, BATCH * TSEQ / 128), 256, 0, stream>>>(
        cx, cwaT, ba, q, BATCH * TSEQ, 3 * CDIM, CDIM);

    // causal flash attention -> y [B,T,C] bf16 (frozen r0 structure)
    flash_attn<<<dim3(BATCH * NHEAD, TSEQ / 128), 256, 0, stream>>>(
        q, q + HEADELEMS, q + 2 * HEADELEMS, y);

    // out = y @ W_proj + b_proj (fp32 out) -- proven 2-buffer + T1 swizzle
    gemm_bt_proj<<<dim3(CDIM / 128, BATCH * TSEQ / 128), 256, 0, stream>>>(
        y, cwpT, bp, (float*)d_out, BATCH * TSEQ, CDIM, CDIM);
}

// Round 10
// 262.729 us; speedup vs baseline: 1.0966x; 1.0153x over previous
//
#include <hip/hip_runtime.h>
#include <hip/hip_bf16.h>
#include <stdint.h>

typedef __bf16 bf16x8 __attribute__((ext_vector_type(8)));
typedef __bf16 bf16x4 __attribute__((ext_vector_type(4)));
typedef float  f32x4  __attribute__((ext_vector_type(4)));

#define MFMA16(a, b, c) __builtin_amdgcn_mfma_f32_16x16x32_bf16((a), (b), (c), 0, 0, 0)

constexpr int BATCH = 4;
constexpr int TSEQ  = 2048;
constexpr int CDIM  = 1024;
constexpr int NHEAD = 16;
constexpr int HSZ   = 64;
constexpr size_t HEADELEMS = (size_t)BATCH * NHEAD * TSEQ * HSZ;  // 8388608

constexpr int LDF = 72;  // flash LDS stride (144 B)

// direct global->LDS DMA, 16 B per lane; LDS dest = wave-uniform base + lane*16
__device__ __forceinline__ void load_lds_128(const __bf16* g, __bf16* l) {
    __builtin_amdgcn_global_load_lds(
        (const __attribute__((address_space(1))) unsigned int*)g,
        (__attribute__((address_space(3))) unsigned int*)l,
        16, 0, 0);
}

// ---------------------------------------------------------------------------
// ROUND-10: fused prep -- one dispatch replaces {conv_f32_bf16, transpose WA,
// transpose WP}. Grid sections (whole blocks per branch, no divergence):
//   [0, 4096)        : fp32->bf16 bulk convert of x (8 elems/thread)
//   [4096, 7168)     : W_attn [1024][3072] -> cwaT [3072][1024] bf16
//   [7168, 8192)     : W_proj [1024][1024] -> cwpT [1024][1024] bf16
// Saves 2 launches + inter-launch gaps; all three sections are HBM-bound.
// ---------------------------------------------------------------------------
__global__ __launch_bounds__(256)
void prep_fused(const float* __restrict__ x, __bf16* __restrict__ cx,
                const float* __restrict__ wa, __bf16* __restrict__ cwaT,
                const float* __restrict__ wp, __bf16* __restrict__ cwpT)
{
    __shared__ __bf16 tile[32][33];
    const int blk = blockIdx.x;

    if (blk < 4096) {
        const int i0 = (blk * 256 + (int)threadIdx.x) * 8;   // < 8388608
        float4 a = *(const float4*)(x + i0);
        float4 b = *(const float4*)(x + i0 + 4);
        bf16x8 o;
        o[0] = (__bf16)a.x; o[1] = (__bf16)a.y; o[2] = (__bf16)a.z; o[3] = (__bf16)a.w;
        o[4] = (__bf16)b.x; o[5] = (__bf16)b.y; o[6] = (__bf16)b.z; o[7] = (__bf16)b.w;
        *(bf16x8*)(cx + i0) = o;
        return;
    }

    const float* src;  __bf16* dst;  int K, N, bidx;
    if (blk < 7168) { src = wa; dst = cwaT; K = 1024; N = 3072; bidx = blk - 4096; }
    else            { src = wp; dst = cwpT; K = 1024; N = 1024; bidx = blk - 7168; }
    const int nbx = N >> 5;
    const int n0 = (bidx % nbx) * 32, k0 = (bidx / nbx) * 32;
    const int tx = threadIdx.x & 31, ty = threadIdx.x >> 5;   // 32 x 8
    #pragma unroll
    for (int i = 0; i < 32; i += 8)
        tile[ty + i][tx] = (__bf16)src[(size_t)(k0 + ty + i) * N + n0 + tx];  // tile[k][n]
    __syncthreads();
    #pragma unroll
    for (int i = 0; i < 32; i += 8)
        dst[(size_t)(n0 + ty + i) * K + k0 + tx] = tile[tx][ty + i];          // dst[n][k]
}

// ---------------------------------------------------------------------------
// GEMM, m97 structure + counted-vmcnt pipeline + T1 XCD swizzle.
// Pipe VALIDATED r5-r8 on QKV (~94 us, MfmaUtil 22.5, absmax pass 4x);
// swizzle VALIDATED r9 (FETCH 71.75 -> 57.5 MB). 3 LDS buffers, depth-2
// prefetch, vmcnt(4) per iter (never 0 mid-loop), raw s_barrier +
// sched_barrier(0). Ordering proof in r5 notes.
// ROUND-10: re-templated (EPI) and applied to the projection GEMM as a
// clean single-variable transfer (r6's bundled attempt was unattributable).
// EPI=0: scatter q[b,h,t,d], k[b,h,t,d], v transposed [b,h,d,t] (bf16).
// EPI=1: row-major fp32 store.
// ---------------------------------------------------------------------------
template<int EPI>
__global__ __launch_bounds__(256, 3)
void gemm_bt_pipe(const __bf16* __restrict__ A, const __bf16* __restrict__ BT,
                  const float* __restrict__ bias, void* __restrict__ outv,
                  int M, int N, int K)
{
    __shared__ __bf16 As[3][128 * 32];   // [buf][row][k], unpadded
    __shared__ __bf16 Bs[3][128 * 32];

    const int t    = threadIdx.x;
    const int wave = t >> 6, lane = t & 63;
    const int quad = lane >> 4, l16 = lane & 15;

    // T1 XCD swizzle: hw-dispatch id -> logical tile id, contiguous per XCD
    const int nbx = (int)gridDim.x;
    int lin = (int)blockIdx.y * nbx + (int)blockIdx.x;
    {
        const int cpx = (nbx * (int)gridDim.y) >> 3;   // nwg % 8 == 0
        lin = (lin & 7) * cpx + (lin >> 3);
    }
    const int bm = (lin / nbx) * 128, bn = (lin % nbx) * 128;
    const int wm = (wave >> 1) * 64, wn = (wave & 1) * 64;

    const int lrow = lane >> 2, lchunk = lane & 3;

    f32x4 acc[4][4];
    #pragma unroll
    for (int i = 0; i < 4; ++i)
        #pragma unroll
        for (int j = 0; j < 4; ++j)
            acc[i][j] = (f32x4){0.f, 0.f, 0.f, 0.f};

    const int c0 = wave * 2, c1 = wave * 2 + 1;
    const __bf16* a0 = A  + (size_t)(bm + 16 * c0 + lrow) * K + 8 * lchunk;
    const __bf16* a1 = A  + (size_t)(bm + 16 * c1 + lrow) * K + 8 * lchunk;
    const __bf16* b0 = BT + (size_t)(bn + 16 * c0 + lrow) * K + 8 * lchunk;
    const __bf16* b1 = BT + (size_t)(bn + 16 * c1 + lrow) * K + 8 * lchunk;

    const int nk = K >> 5;

#define STAGE(buf, kofs) do { \
    load_lds_128(a0 + (kofs), &As[buf][c0 * 512]); \
    load_lds_128(a1 + (kofs), &As[buf][c1 * 512]); \
    load_lds_128(b0 + (kofs), &Bs[buf][c0 * 512]); \
    load_lds_128(b1 + (kofs), &Bs[buf][c1 * 512]); } while (0)

    // prologue: tiles 0 and 1 in flight
    STAGE(0, 0);
    if (nk > 1) STAGE(1, 32);

    int cur = 0;
    for (int it = 0; it < nk; ++it) {
        if (it + 1 < nk) asm volatile("s_waitcnt vmcnt(4)" ::: "memory");
        else             asm volatile("s_waitcnt vmcnt(0)" ::: "memory");
        __builtin_amdgcn_s_barrier();
        __builtin_amdgcn_sched_barrier(0);

        if (it + 2 < nk) {
            const int stg = (cur >= 1) ? cur - 1 : cur + 2;   // (cur+2)%3
            STAGE(stg, (it + 2) * 32);
        }

        bf16x8 af[4], bfr[4];
        #pragma unroll
        for (int i = 0; i < 4; ++i)
            af[i]  = *(const bf16x8*)(&As[cur][(wm + i * 16 + l16) * 32 + quad * 8]);
        #pragma unroll
        for (int i = 0; i < 4; ++i)
            bfr[i] = *(const bf16x8*)(&Bs[cur][(wn + i * 16 + l16) * 32 + quad * 8]);
        #pragma unroll
        for (int mi = 0; mi < 4; ++mi)
            #pragma unroll
            for (int ni = 0; ni < 4; ++ni)
                acc[mi][ni] = MFMA16(af[mi], bfr[ni], acc[mi][ni]);

        cur = (cur + 1 >= 3) ? 0 : cur + 1;
    }
#undef STAGE

    if constexpr (EPI == 0) {
        __bf16* outp = (__bf16*)outv;
        #pragma unroll
        for (int ni = 0; ni < 4; ++ni) {
            const int col = bn + wn + ni * 16 + l16;          // 0..3071
            const float bv = bias[col];
            const int which = col >> 10;                      // 0=q 1=k 2=v
            const int c = col & 1023;
            const int h = c >> 6, d = c & 63;
            #pragma unroll
            for (int mi = 0; mi < 4; ++mi)
                #pragma unroll
                for (int r = 0; r < 4; ++r) {
                    const int row = bm + wm + mi * 16 + quad * 4 + r;  // 0..8191
                    const int bb = row >> 11, tt = row & 2047;
                    size_t idx;
                    if (which == 2)  // v transposed: [b,h,d,t]
                        idx = 2 * HEADELEMS + ((((size_t)bb * NHEAD + h) * HSZ + d) * TSEQ + tt);
                    else
                        idx = (size_t)which * HEADELEMS
                            + ((((size_t)bb * NHEAD + h) * TSEQ + tt) * HSZ + d);
                    outp[idx] = (__bf16)(acc[mi][ni][r] + bv);
                }
        }
    } else {
        float* outp = (float*)outv;
        #pragma unroll
        for (int ni = 0; ni < 4; ++ni) {
            const int col = bn + wn + ni * 16 + l16;
            const float bv = bias[col];
            #pragma unroll
            for (int mi = 0; mi < 4; ++mi)
                #pragma unroll
                for (int r = 0; r < 4; ++r) {
                    const int row = bm + wm + mi * 16 + quad * 4 + r;
                    outp[(size_t)row * N + col] = acc[mi][ni][r] + bv;
                }
        }
    }
}

// ---------------------------------------------------------------------------
// Flash attention (causal), UNNORMALIZED, S^T formulation -- the r0/r5
// PROVEN structure (92.5 us, Occ 28%). FROZEN: four restructures (T14
// reg-prefetch, 2-wave blocks, causal pairing, split-K) all regressed
// +5..+19 us. KVBLK=128 eliminated on paper (LDS ~54KB -> 2 blocks/CU,
// same occupancy cliff as r6). Remaining headroom needs the co-designed
// 8-warp ladder, not piecewise grafts.
// Q,K: [B*NH, T, 64]; V: [B*NH, 64, T] (transposed). Y: [B,T,C] bf16.
// ---------------------------------------------------------------------------
__global__ __launch_bounds__(256, 4)
void flash_attn(const __bf16* __restrict__ Q, const __bf16* __restrict__ Kg,
                const __bf16* __restrict__ Vg, __bf16* __restrict__ Y)
{
    __shared__ __bf16 Ks[64 * LDF];      // [key][d]
    __shared__ __bf16 Vs[64 * LDF];      // [d][key]
    __shared__ __bf16 Ps[4][32 * LDF];   // per-wave [q][key] (wave-private)

    const int t = threadIdx.x, wave = t >> 6, lane = t & 63;
    const int quad = lane >> 4, l16 = lane & 15;
    const int bh = blockIdx.x;
    const int q0 = ((int)gridDim.y - 1 - (int)blockIdx.y) * 128;  // longest first
    const size_t base = (size_t)bh * TSEQ * HSZ;

    const float sc = 0.125f * 1.44269504088896341f;  // log2(e)/sqrt(HS)

    // Q fragments (B-operand: n=l16 -> q row), pre-scaled by sc
    bf16x8 qf[2][2];
    #pragma unroll
    for (int mi = 0; mi < 2; ++mi) {
        const int qrow = q0 + wave * 32 + mi * 16 + l16;
        #pragma unroll
        for (int h = 0; h < 2; ++h) {
            bf16x8 raw = *(const bf16x8*)(Q + base + (size_t)qrow * HSZ + h * 32 + quad * 8);
            #pragma unroll
            for (int j = 0; j < 8; ++j) qf[mi][h][j] = (__bf16)((float)raw[j] * sc);
        }
    }

    bf16x8 ones;
    #pragma unroll
    for (int j = 0; j < 8; ++j) ones[j] = (__bf16)1.0f;

    f32x4 oacc[2][4];   // [mi][dt], C-layout row=q(quad*4+r), col=d(l16)
    f32x4 lacc[2];      // [mi],     row=q(quad*4+r), all cols equal
    #pragma unroll
    for (int mi = 0; mi < 2; ++mi) {
        lacc[mi] = (f32x4){0.f, 0.f, 0.f, 0.f};
        #pragma unroll
        for (int dt = 0; dt < 4; ++dt) oacc[mi][dt] = (f32x4){0.f, 0.f, 0.f, 0.f};
    }

    const int s_row = t >> 2, s_c16 = (t & 3) * 16;

    const int iters = q0 / 64 + 2;
    for (int it = 0; it < iters; ++it) {
        const int kt = it * 64;
        {   // stage K [key][d]
            const __bf16* kp = Kg + base + (size_t)(kt + s_row) * HSZ + s_c16;
            bf16x8 v0 = *(const bf16x8*)kp;
            bf16x8 v1 = *(const bf16x8*)(kp + 8);
            *(bf16x8*)(&Ks[s_row * LDF + s_c16])     = v0;
            *(bf16x8*)(&Ks[s_row * LDF + s_c16 + 8]) = v1;
        }
        {   // stage V [d][key]
            const __bf16* vp = Vg + base + (size_t)s_row * TSEQ + kt + s_c16;
            bf16x8 v0 = *(const bf16x8*)vp;
            bf16x8 v1 = *(const bf16x8*)(vp + 8);
            *(bf16x8*)(&Vs[s_row * LDF + s_c16])     = v0;
            *(bf16x8*)(&Vs[s_row * LDF + s_c16 + 8]) = v1;
        }
        __syncthreads();

        const bool active = (kt <= q0 + wave * 32 + 31);
        if (active) {
            // ---- S^T = K·Q^T : [4 key-tiles][2 q-tiles], C row=key, col=q ----
            f32x4 st[4][2];
            #pragma unroll
            for (int ktl = 0; ktl < 4; ++ktl) {
                bf16x8 kf0 = *(const bf16x8*)(&Ks[(ktl * 16 + l16) * LDF + quad * 8]);
                bf16x8 kf1 = *(const bf16x8*)(&Ks[(ktl * 16 + l16) * LDF + 32 + quad * 8]);
                #pragma unroll
                for (int mi = 0; mi < 2; ++mi) {
                    f32x4 a = (f32x4){0.f, 0.f, 0.f, 0.f};
                    a = MFMA16(kf0, qf[mi][0], a);
                    a = MFMA16(kf1, qf[mi][1], a);
                    st[ktl][mi] = a;
                }
            }

            // ---- causal mask (near diagonal only) ----
            if (kt + 63 >= q0 + wave * 32) {
                #pragma unroll
                for (int ktl = 0; ktl < 4; ++ktl)
                    #pragma unroll
                    for (int mi = 0; mi < 2; ++mi)
                        #pragma unroll
                        for (int r = 0; r < 4; ++r) {
                            const int key = kt + ktl * 16 + quad * 4 + r;
                            const int qr  = q0 + wave * 32 + mi * 16 + l16;
                            if (key > qr) st[ktl][mi][r] = -1e30f;
                        }
            }

            // ---- P = exp2(S^T), packed b64 writes into Ps[q][key] ----
            #pragma unroll
            for (int ktl = 0; ktl < 4; ++ktl)
                #pragma unroll
                for (int mi = 0; mi < 2; ++mi) {
                    bf16x4 pv;
                    #pragma unroll
                    for (int r = 0; r < 4; ++r)
                        pv[r] = (__bf16)exp2f(st[ktl][mi][r]);
                    *(bf16x4*)(&Ps[wave][(mi * 16 + l16) * LDF + ktl * 16 + quad * 4]) = pv;
                }

            // wave-local fence: DS writes complete before reload (wave-private Ps)
            asm volatile("s_waitcnt lgkmcnt(0)" ::: "memory");

            // ---- O += P·V^T, l += P·1 ----
            bf16x8 pf[2][2];
            #pragma unroll
            for (int mi = 0; mi < 2; ++mi) {
                pf[mi][0] = *(const bf16x8*)(&Ps[wave][(mi * 16 + l16) * LDF + quad * 8]);
                pf[mi][1] = *(const bf16x8*)(&Ps[wave][(mi * 16 + l16) * LDF + 32 + quad * 8]);
                lacc[mi] = MFMA16(pf[mi][0], ones, lacc[mi]);
                lacc[mi] = MFMA16(pf[mi][1], ones, lacc[mi]);
            }
            #pragma unroll
            for (int dt = 0; dt < 4; ++dt) {
                bf16x8 vf0 = *(const bf16x8*)(&Vs[(dt * 16 + l16) * LDF + quad * 8]);
                bf16x8 vf1 = *(const bf16x8*)(&Vs[(dt * 16 + l16) * LDF + 32 + quad * 8]);
                #pragma unroll
                for (int mi = 0; mi < 2; ++mi) {
                    oacc[mi][dt] = MFMA16(pf[mi][0], vf0, oacc[mi][dt]);
                    oacc[mi][dt] = MFMA16(pf[mi][1], vf1, oacc[mi][dt]);
                }
            }
        }
        __syncthreads();
    }

    // ---- epilogue: y = O / l (both C-layout, no cross-lane moves) ----
    const int b = bh >> 4, h = bh & 15;
    #pragma unroll
    for (int mi = 0; mi < 2; ++mi) {
        const f32x4 linv = {1.f / lacc[mi][0], 1.f / lacc[mi][1],
                            1.f / lacc[mi][2], 1.f / lacc[mi][3]};
        #pragma unroll
        for (int dt = 0; dt < 4; ++dt)
            #pragma unroll
            for (int r = 0; r < 4; ++r) {
                const int tt = q0 + wave * 32 + mi * 16 + quad * 4 + r;
                const int d  = dt * 16 + l16;
                Y[((size_t)(b * TSEQ + tt) * CDIM) + h * HSZ + d] =
                    (__bf16)(oacc[mi][dt][r] * linv[r]);
            }
    }
}

// ---------------------------------------------------------------------------
extern "C" void kernel_launch(void* const* d_in, const int* in_sizes, int n_in,
                              void* d_out, int out_size, void* d_ws, size_t ws_size,
                              hipStream_t stream)
{
    const int NX = 8388608, NWA = 3145728, NWP = 1048576;
    char* wsb = (char*)d_ws;

    size_t off = 0;
    __bf16* cx   = (__bf16*)(wsb + off); off += (size_t)2 * NX;
    __bf16* cwaT = (__bf16*)(wsb + off); off += (size_t)2 * NWA;   // [3072][1024]
    __bf16* cwpT = (__bf16*)(wsb + off); off += (size_t)2 * NWP;   // [1024][1024]
    __bf16* q    = (__bf16*)(wsb + off);
    __bf16* y    = q + 3 * HEADELEMS;

    const float* xf = (const float*)d_in[0];
    const float* ba = (const float*)d_in[2];
    const float* bp = (const float*)d_in[4];

    // fused prep: convert x + transpose both weight matrices (one dispatch)
    prep_fused<<<8192, 256, 0, stream>>>(
        xf, cx, (const float*)d_in[1], cwaT, (const float*)d_in[3], cwpT);

    // qkv = x @ W_attn + b_attn -> q/k [b,h,t,d], v [b,h,d,t]
    // (validated counted-vmcnt pipe + T1 XCD swizzle)
    gemm_bt_pipe<0><<<dim3(3 * CDIM / 128, BATCH * TSEQ / 128), 256, 0, stream>>>(
        cx, cwaT, ba, q, BATCH * TSEQ, 3 * CDIM, CDIM);

    // causal flash attention -> y [B,T,C] bf16 (frozen r0 structure)
    flash_attn<<<dim3(BATCH * NHEAD, TSEQ / 128), 256, 0, stream>>>(
        q, q + HEADELEMS, q + 2 * HEADELEMS, y);

    // out = y @ W_proj + b_proj (fp32 out) -- pipe + swizzle transfer (r10)
    gemm_bt_pipe<1><<<dim3(CDIM / 128, BATCH * TSEQ / 128), 256, 0, stream>>>(
        y, cwpT, bp, d_out, BATCH * TSEQ, CDIM, CDIM);
}